// Round 15
// baseline (154.571 us; speedup 1.0000x reference)
//
#include <hip/hip_runtime.h>
#include <math.h>

#define TOKENS 16384
#define HID    2048
#define NCH    16
#define TPB    128         // tokens per block-group (2 K-split blocks share it)

typedef float f4 __attribute__((ext_vector_type(4)));
typedef short s8v __attribute__((ext_vector_type(8)));

// ws byte layout:
//   w1   [0, 256KB)            bf16 plane1 [64][2048]
//   w2   [256KB, 512KB)        bf16 plane2 [64][2048]
//   gcnt [524288, +512)        unsigned[128] group tickets (zeroed by k_pack)
//   bp   [525312, +64KB)       float[128][128] aux partials (by finisher)
//   part [655360, +8MB)        fp32 [2][16384][64] partial logits
#define WS_W2   262144
#define WS_GCNT 524288
#define WS_BP   525312
#define WS_PART 655360

__device__ __forceinline__ unsigned short bf16rne(float x) {
  unsigned u = __float_as_uint(x);
  return (unsigned short)((u + 0x7FFFu + ((u >> 16) & 1u)) >> 16);
}

__device__ __forceinline__ void gl16(const void* g, const void* l) {
  __builtin_amdgcn_global_load_lds(
      (const __attribute__((address_space(1))) void*)g,
      (__attribute__((address_space(3))) void*)l, 16, 0, 0);
}

#define BARK(N) { asm volatile("s_waitcnt vmcnt(" #N ") lgkmcnt(0)" ::: "memory"); \
  __builtin_amdgcn_sched_barrier(0); __builtin_amdgcn_s_barrier(); \
  __builtin_amdgcn_sched_barrier(0); }

// fp32 weights -> two bf16 planes; also zeroes the group tickets
__global__ __launch_bounds__(256) void k_pack(const float* __restrict__ gw,
                                              unsigned short* __restrict__ w1,
                                              unsigned short* __restrict__ w2,
                                              unsigned* __restrict__ gcnt) {
  if (blockIdx.x == 0 && threadIdx.x < 128) gcnt[threadIdx.x] = 0u;
  int gid = blockIdx.x * 256 + threadIdx.x;   // 16384 threads * 8 els
  int m = gid * 8;
  f4 a = *(const f4*)(gw + m);
  f4 b = *(const f4*)(gw + m + 4);
  float av[8] = {a.x, a.y, a.z, a.w, b.x, b.y, b.z, b.w};
  unsigned short p1[8], p2[8];
  #pragma unroll
  for (int i = 0; i < 8; ++i) {
    unsigned short h = bf16rne(av[i]);
    p1[i] = h;
    float r = av[i] - __uint_as_float((unsigned)h << 16);
    p2[i] = bf16rne(r);
  }
  *(s8v*)(w1 + m) = *(s8v*)p1;
  *(s8v*)(w2 + m) = *(s8v*)p2;
}

__global__ __launch_bounds__(512, 1) void k_main(const float* __restrict__ hid,
                                                 const unsigned short* __restrict__ w1,
                                                 const unsigned short* __restrict__ w2,
                                                 float* __restrict__ part,
                                                 unsigned* __restrict__ gcnt,
                                                 float* __restrict__ out,
                                                 float* __restrict__ bp) {
  // 3 buffers * 49152B: A fp32 [128 tok][256B] (32KB) + w1 [64 e][128B] (8KB) + w2 (8KB)
  __shared__ __align__(16) char lds[147456];
  const int tid = threadIdx.x, wave = tid >> 6, lane = tid & 63;
  const int l15 = lane & 15, ks = lane >> 4;
  const int tg = blockIdx.x >> 1, kq = blockIdx.x & 1;   // token-group, K-half
  const int tok0 = tg * TPB;

  // ---- staging sources (64B-line-local granule permutation; LDS dest linear) ----
  const char* hb = (const char*)hid;
  size_t asrc[4]; int adst[4];
  #pragma unroll
  for (int j = 0; j < 4; ++j) {
    int u = j * 512 + tid;
    int row = u >> 4, g = u & 15;
    asrc[j] = (size_t)(tok0 + row) * 8192 + (size_t)kq * 4096
            + (size_t)((g ^ (row & 3)) << 4);
    adst[j] = u * 16;
  }
  // B: waves 0-3 stage w1, waves 4-7 stage w2 (2 granules/thread)
  const char* wpb = (tid < 256) ? (const char*)w1 : (const char*)w2;
  const int bdst0 = (tid < 256) ? 32768 : 40960;
  const int tt = tid & 255;
  size_t bsrc[2]; int bdst[2];
  #pragma unroll
  for (int j = 0; j < 2; ++j) {
    int v = j * 256 + tt;
    int e = v >> 3, g = v & 7;
    bsrc[j] = (size_t)e * 4096 + (size_t)kq * 2048 + (size_t)((g ^ (e & 3)) << 4);
    bdst[j] = bdst0 + v * 16;
  }

  f4 acc[4] = {{0.f,0.f,0.f,0.f},{0.f,0.f,0.f,0.f},{0.f,0.f,0.f,0.f},{0.f,0.f,0.f,0.f}};
  const int arow = wave * 16 + l15, asw = arow & 3;

  auto stage = [&](int c, int bufb) {
    #pragma unroll
    for (int j = 0; j < 4; ++j)
      gl16(hb + asrc[j] + (size_t)c * 256, lds + bufb + adst[j]);
    #pragma unroll
    for (int j = 0; j < 2; ++j)
      gl16(wpb + bsrc[j] + (size_t)c * 128, lds + bufb + bdst[j]);
  };

  auto compute = [&](int bufb) {
    #pragma unroll
    for (int s = 0; s < 2; ++s) {
      int g0 = (s * 8 + ks * 2) ^ asw;
      int g1 = (s * 8 + ks * 2 + 1) ^ asw;
      f4 a0 = *(const f4*)(lds + bufb + arow * 256 + g0 * 16);
      f4 a1 = *(const f4*)(lds + bufb + arow * 256 + g1 * 16);
      float av[8] = {a0.x, a0.y, a0.z, a0.w, a1.x, a1.y, a1.z, a1.w};
      unsigned short p1[8], p2[8];
      #pragma unroll
      for (int i = 0; i < 8; ++i) {
        unsigned short h = bf16rne(av[i]);
        p1[i] = h;
        float r = av[i] - __uint_as_float((unsigned)h << 16);
        p2[i] = bf16rne(r);
      }
      s8v af1 = *(s8v*)p1;
      s8v af2 = *(s8v*)p2;
      #pragma unroll
      for (int nj = 0; nj < 4; ++nj) {
        int e = nj * 16 + l15;
        int g = (s * 4 + ks) ^ (e & 3);
        s8v bw1 = *(const s8v*)(lds + bufb + 32768 + e * 128 + g * 16);
        s8v bw2 = *(const s8v*)(lds + bufb + 40960 + e * 128 + g * 16);
        acc[nj] = __builtin_amdgcn_mfma_f32_16x16x32_bf16(af1, bw1, acc[nj], 0, 0, 0);
        acc[nj] = __builtin_amdgcn_mfma_f32_16x16x32_bf16(af1, bw2, acc[nj], 0, 0, 0);
        acc[nj] = __builtin_amdgcn_mfma_f32_16x16x32_bf16(af2, bw1, acc[nj], 0, 0, 0);
      }
    }
  };

  stage(0, 0);
  stage(1, 49152);
  BARK(6);

  for (int c = 0; c < NCH; ++c) {
    const int bufb = (c % 3) * 49152;
    if (c + 2 < NCH) {
      stage(c + 2, ((c + 2) % 3) * 49152);
      compute(bufb);
      BARK(6);
    } else if (c + 1 < NCH) {
      compute(bufb);
      BARK(0);
    } else {
      compute(bufb);
    }
  }

  // ---- write own partial logits: part[kq][token][expert] ----
  #pragma unroll
  for (int nj = 0; nj < 4; ++nj) {
    int e = nj * 16 + l15;
    #pragma unroll
    for (int r = 0; r < 4; ++r) {
      int tl = wave * 16 + ks * 4 + r;
      part[((size_t)kq * TOKENS + (size_t)(tok0 + tl)) * 64 + e] = acc[nj][r];
    }
  }
  __threadfence();                 // release: partial visible before ticket
  __shared__ unsigned ticket;
  if (tid == 0) ticket = atomicAdd(&gcnt[tg], 1u);
  __syncthreads();                 // also fences all waves past compute
  if (ticket == 0) return;         // first arrival: partial writer only
  __threadfence();                 // acquire: other half's writes visible

  // ---- finisher: park own acc [128 tok][68], add other half, softmax ----
  float* lf = (float*)lds;
  #pragma unroll
  for (int nj = 0; nj < 4; ++nj)
    #pragma unroll
    for (int r = 0; r < 4; ++r)
      lf[(wave * 16 + ks * 4 + r) * 68 + nj * 16 + l15] = acc[nj][r];
  __syncthreads();

  {
    const float* po = part + (size_t)(1 - kq) * TOKENS * 64 + (size_t)tok0 * 64;
    const int t4 = tid >> 2, eb = (tid & 3) * 16;
    #pragma unroll
    for (int j = 0; j < 4; ++j) {
      f4 v = *(const f4*)(po + (size_t)t4 * 64 + eb + j * 4);
      lf[t4 * 68 + eb + j * 4 + 0] += v.x;
      lf[t4 * 68 + eb + j * 4 + 1] += v.y;
      lf[t4 * 68 + eb + j * 4 + 2] += v.z;
      lf[t4 * 68 + eb + j * 4 + 3] += v.w;
    }
  }
  __syncthreads();

  float spacc = 0.f, cntacc = 0.f;
  for (int it = 0; it < 16; ++it) {
    const int tl = wave * 16 + it;
    float lg = lf[tl * 68 + lane];
    float m1 = lg;
    #pragma unroll
    for (int d = 1; d < 64; d <<= 1) m1 = fmaxf(m1, __shfl_xor(m1, d));
    int c0 = (lg == m1) ? lane : 64;
    #pragma unroll
    for (int d = 1; d < 64; d <<= 1) c0 = min(c0, __shfl_xor(c0, d));
    float lx1 = (lane == c0) ? -INFINITY : lg;
    float m2 = lx1;
    #pragma unroll
    for (int d = 1; d < 64; d <<= 1) m2 = fmaxf(m2, __shfl_xor(m2, d));
    int c1 = (lx1 == m2) ? lane : 64;
    #pragma unroll
    for (int d = 1; d < 64; d <<= 1) c1 = min(c1, __shfl_xor(c1, d));

    float p = __expf(lg - m1);
    float Z = p;
    #pragma unroll
    for (int d = 1; d < 64; d <<= 1) Z += __shfl_xor(Z, d);
    spacc = fmaf(p, 1.f / Z, spacc);
    cntacc += ((lane == c0) ? 1.f : 0.f) + ((lane == c1) ? 1.f : 0.f);

    float gr = __expf(m2 - m1);
    float r0 = 1.f / (1.f + gr);
    if (lane == 0) {
      int t = tok0 + tl;
      out[(size_t)t * 2]     = r0;
      out[(size_t)t * 2 + 1] = gr * r0;
      out[(size_t)TOKENS * 2 + t * 2]     = (float)c0;
      out[(size_t)TOKENS * 2 + t * 2 + 1] = (float)c1;
    }
  }

  float* red = lf + 8704;
  red[wave * 128 + lane]      = spacc;
  red[wave * 128 + 64 + lane] = cntacc;
  __syncthreads();
  if (tid < 128) {
    float s = 0.f;
    #pragma unroll
    for (int w = 0; w < 8; ++w) s += red[w * 128 + tid];
    bp[(size_t)tg * 128 + tid] = s;
  }
}

__global__ __launch_bounds__(128) void k_loss(const float* __restrict__ bp,
                                              float* __restrict__ out) {
  const int tid = threadIdx.x;
  float s = 0.f;
  #pragma unroll 8
  for (int g = 0; g < 128; ++g) s += bp[(size_t)g * 128 + tid];
  __shared__ float red[128];
  red[tid] = s;
  __syncthreads();
  if (tid < 64) {
    float v = red[tid] * red[64 + tid];   // sumprob_e * count_e
    #pragma unroll
    for (int d = 1; d < 64; d <<= 1) v += __shfl_xor(v, d);
    if (tid == 0)
      out[(size_t)TOKENS * 4] = 0.01f * 64.f * v / (16384.f * 16384.f);
  }
}

extern "C" void kernel_launch(void* const* d_in, const int* in_sizes, int n_in,
                              void* d_out, int out_size, void* d_ws, size_t ws_size,
                              hipStream_t stream) {
  (void)in_sizes; (void)n_in; (void)out_size; (void)ws_size;
  const float* hid = (const float*)d_in[0];
  const float* gw  = (const float*)d_in[1];
  float* out = (float*)d_out;
  char* ws = (char*)d_ws;
  unsigned short* w1 = (unsigned short*)ws;
  unsigned short* w2 = (unsigned short*)(ws + WS_W2);
  unsigned* gcnt = (unsigned*)(ws + WS_GCNT);
  float* bp    = (float*)(ws + WS_BP);
  float* part  = (float*)(ws + WS_PART);

  k_pack<<<64, 256, 0, stream>>>(gw, w1, w2, gcnt);
  k_main<<<256, 512, 0, stream>>>(hid, w1, w2, part, gcnt, out, bp);
  k_loss<<<1, 128, 0, stream>>>(bp, out);
}

// Round 16
// 58.489 us; speedup vs baseline: 2.6427x; 2.6427x over previous
//
#include <hip/hip_runtime.h>
#include <math.h>

#define TOKENS 16384
#define HID    2048
#define NCH    16
#define TPB    128         // tokens per block-group (2 K-split blocks share it)

typedef float f4 __attribute__((ext_vector_type(4)));
typedef short s8v __attribute__((ext_vector_type(8)));

// ws byte layout:
//   w1   [0, 256KB)          bf16 plane1 [64][2048]   (dead after k_main)
//   w2   [256KB, 512KB)      bf16 plane2 [64][2048]   (dead after k_main)
//   part [512KB, 512KB+8MB)  fp32 [2][16384][64] partial logits
//   bp   [0, 128KB)          reuses w1 region (written by k_finish)
#define WS_W2   262144
#define WS_PART 524288

__device__ __forceinline__ unsigned short bf16rne(float x) {
  unsigned u = __float_as_uint(x);
  return (unsigned short)((u + 0x7FFFu + ((u >> 16) & 1u)) >> 16);
}

__device__ __forceinline__ void gl16(const void* g, const void* l) {
  __builtin_amdgcn_global_load_lds(
      (const __attribute__((address_space(1))) void*)g,
      (__attribute__((address_space(3))) void*)l, 16, 0, 0);
}

#define BARK(N) { asm volatile("s_waitcnt vmcnt(" #N ") lgkmcnt(0)" ::: "memory"); \
  __builtin_amdgcn_sched_barrier(0); __builtin_amdgcn_s_barrier(); \
  __builtin_amdgcn_sched_barrier(0); }

// fp32 weights -> two bf16 planes (w ~= w1 + w2, residual ~2^-18)
__global__ __launch_bounds__(256) void k_pack(const float* __restrict__ gw,
                                              unsigned short* __restrict__ w1,
                                              unsigned short* __restrict__ w2) {
  int gid = blockIdx.x * 256 + threadIdx.x;   // 16384 threads * 8 els
  int m = gid * 8;
  f4 a = *(const f4*)(gw + m);
  f4 b = *(const f4*)(gw + m + 4);
  float av[8] = {a.x, a.y, a.z, a.w, b.x, b.y, b.z, b.w};
  unsigned short p1[8], p2[8];
  #pragma unroll
  for (int i = 0; i < 8; ++i) {
    unsigned short h = bf16rne(av[i]);
    p1[i] = h;
    float r = av[i] - __uint_as_float((unsigned)h << 16);
    p2[i] = bf16rne(r);
  }
  *(s8v*)(w1 + m) = *(s8v*)p1;
  *(s8v*)(w2 + m) = *(s8v*)p2;
}

__global__ __launch_bounds__(512, 1) void k_main(const float* __restrict__ hid,
                                                 const unsigned short* __restrict__ w1,
                                                 const unsigned short* __restrict__ w2,
                                                 float* __restrict__ part) {
  // 3 buffers * 49152B: A fp32 [128 tok][256B] (32KB) + w1 [64 e][128B] (8KB) + w2 (8KB)
  __shared__ __align__(16) char lds[147456];
  const int tid = threadIdx.x, wave = tid >> 6, lane = tid & 63;
  const int l15 = lane & 15, ks = lane >> 4;
  const int tg = blockIdx.x >> 1, kq = blockIdx.x & 1;   // token-group, K-half
  const int tok0 = tg * TPB;

  // ---- staging sources (64B-line-local granule permutation; LDS dest linear) ----
  const char* hb = (const char*)hid;
  size_t asrc[4]; int adst[4];
  #pragma unroll
  for (int j = 0; j < 4; ++j) {
    int u = j * 512 + tid;
    int row = u >> 4, g = u & 15;
    asrc[j] = (size_t)(tok0 + row) * 8192 + (size_t)kq * 4096
            + (size_t)((g ^ (row & 3)) << 4);
    adst[j] = u * 16;
  }
  // B: waves 0-3 stage w1, waves 4-7 stage w2 (2 granules/thread)
  const char* wpb = (tid < 256) ? (const char*)w1 : (const char*)w2;
  const int bdst0 = (tid < 256) ? 32768 : 40960;
  const int tt = tid & 255;
  size_t bsrc[2]; int bdst[2];
  #pragma unroll
  for (int j = 0; j < 2; ++j) {
    int v = j * 256 + tt;
    int e = v >> 3, g = v & 7;
    bsrc[j] = (size_t)e * 4096 + (size_t)kq * 2048 + (size_t)((g ^ (e & 3)) << 4);
    bdst[j] = bdst0 + v * 16;
  }

  f4 acc[4] = {{0.f,0.f,0.f,0.f},{0.f,0.f,0.f,0.f},{0.f,0.f,0.f,0.f},{0.f,0.f,0.f,0.f}};
  const int arow = wave * 16 + l15, asw = arow & 3;

  auto stage = [&](int c, int bufb) {
    #pragma unroll
    for (int j = 0; j < 4; ++j)
      gl16(hb + asrc[j] + (size_t)c * 256, lds + bufb + adst[j]);
    #pragma unroll
    for (int j = 0; j < 2; ++j)
      gl16(wpb + bsrc[j] + (size_t)c * 128, lds + bufb + bdst[j]);
  };

  auto compute = [&](int bufb) {
    #pragma unroll
    for (int s = 0; s < 2; ++s) {
      int g0 = (s * 8 + ks * 2) ^ asw;
      int g1 = (s * 8 + ks * 2 + 1) ^ asw;
      f4 a0 = *(const f4*)(lds + bufb + arow * 256 + g0 * 16);
      f4 a1 = *(const f4*)(lds + bufb + arow * 256 + g1 * 16);
      float av[8] = {a0.x, a0.y, a0.z, a0.w, a1.x, a1.y, a1.z, a1.w};
      unsigned short p1[8], p2[8];
      #pragma unroll
      for (int i = 0; i < 8; ++i) {
        unsigned short h = bf16rne(av[i]);
        p1[i] = h;
        float r = av[i] - __uint_as_float((unsigned)h << 16);
        p2[i] = bf16rne(r);
      }
      s8v af1 = *(s8v*)p1;
      s8v af2 = *(s8v*)p2;
      #pragma unroll
      for (int nj = 0; nj < 4; ++nj) {
        int e = nj * 16 + l15;
        int g = (s * 4 + ks) ^ (e & 3);
        s8v bw1 = *(const s8v*)(lds + bufb + 32768 + e * 128 + g * 16);
        s8v bw2 = *(const s8v*)(lds + bufb + 40960 + e * 128 + g * 16);
        acc[nj] = __builtin_amdgcn_mfma_f32_16x16x32_bf16(af1, bw1, acc[nj], 0, 0, 0);
        acc[nj] = __builtin_amdgcn_mfma_f32_16x16x32_bf16(af1, bw2, acc[nj], 0, 0, 0);
        acc[nj] = __builtin_amdgcn_mfma_f32_16x16x32_bf16(af2, bw1, acc[nj], 0, 0, 0);
      }
    }
  };

  stage(0, 0);
  stage(1, 49152);
  BARK(6);

  for (int c = 0; c < NCH; ++c) {
    const int bufb = (c % 3) * 49152;
    if (c + 2 < NCH) {
      stage(c + 2, ((c + 2) % 3) * 49152);
      compute(bufb);
      BARK(6);
    } else if (c + 1 < NCH) {
      compute(bufb);
      BARK(0);
    } else {
      compute(bufb);
    }
  }

  // ---- write partial logits: part[kq][token][expert] ----
  #pragma unroll
  for (int nj = 0; nj < 4; ++nj) {
    int e = nj * 16 + l15;
    #pragma unroll
    for (int r = 0; r < 4; ++r) {
      int tl = wave * 16 + ks * 4 + r;
      part[((size_t)kq * TOKENS + (size_t)(tok0 + tl)) * 64 + e] = acc[nj][r];
    }
  }
}

// sum the two K-halves, softmax/top-2/aux partials (R3-verified structure)
__global__ __launch_bounds__(64) void k_finish(const float* __restrict__ part,
                                               float* __restrict__ out,
                                               float* __restrict__ bp) {
  const int lane = threadIdx.x;
  const int t = blockIdx.x * 64 + lane;

  float lg[64];
  const float* p0 = part + (size_t)t * 64;
  const float* p1 = part + (size_t)TOKENS * 64 + (size_t)t * 64;
  #pragma unroll
  for (int e = 0; e < 64; e += 4) {
    f4 a = *(const f4*)(p0 + e);
    f4 b = *(const f4*)(p1 + e);
    lg[e]     = a.x + b.x;
    lg[e + 1] = a.y + b.y;
    lg[e + 2] = a.z + b.z;
    lg[e + 3] = a.w + b.w;
  }

  float m = lg[0];
  #pragma unroll
  for (int e = 1; e < 64; ++e) m = fmaxf(m, lg[e]);
  float s = 0.f;
  #pragma unroll
  for (int e = 0; e < 64; ++e) { lg[e] = __expf(lg[e] - m); s += lg[e]; }
  const float inv = 1.f / s;

  // top-2 on exp values (monotone); strict '>' == lax.top_k tie-break
  float b0 = -1.f, b1 = -1.f;
  int i0 = 0, i1 = 0;
  #pragma unroll
  for (int e = 0; e < 64; ++e) {
    float p = lg[e];
    if (p > b0)      { b1 = b0; i1 = i0; b0 = p; i0 = e; }
    else if (p > b1) { b1 = p; i1 = e; }
  }
  const float rs = 1.f / (b0 + b1);
  out[(size_t)t * 2]                  = b0 * rs;
  out[(size_t)t * 2 + 1]              = b1 * rs;
  out[(size_t)TOKENS * 2 + t * 2]     = (float)i0;
  out[(size_t)TOKENS * 2 + t * 2 + 1] = (float)i1;

  // per-expert partials: softmax-prob sums (butterfly) + top-2 counts (ballot)
  float my_sp = 0.f, my_cnt = 0.f;
  #pragma unroll
  for (int e = 0; e < 64; ++e) {
    float x = lg[e] * inv;
    #pragma unroll
    for (int d = 1; d < 64; d <<= 1) x += __shfl_xor(x, d);
    float c = (float)(__popcll(__ballot(i0 == e)) + __popcll(__ballot(i1 == e)));
    if (lane == e) { my_sp = x; my_cnt = c; }
  }
  bp[(size_t)blockIdx.x * 128 + lane]      = my_sp;
  bp[(size_t)blockIdx.x * 128 + 64 + lane] = my_cnt;
}

// fused two-stage loss reduction (one block)
__global__ __launch_bounds__(128) void k_loss(const float* __restrict__ bp,
                                              float* __restrict__ out) {
  const int tid = threadIdx.x;
  float s = 0.f;
  #pragma unroll 8
  for (int g = 0; g < 256; ++g) s += bp[(size_t)g * 128 + tid];
  __shared__ float red[128];
  red[tid] = s;
  __syncthreads();
  if (tid < 64) {
    float v = red[tid] * red[64 + tid];   // sumprob_e * count_e
    #pragma unroll
    for (int d = 1; d < 64; d <<= 1) v += __shfl_xor(v, d);
    if (tid == 0)
      out[(size_t)TOKENS * 4] = 0.01f * 64.f * v / (16384.f * 16384.f);
  }
}

extern "C" void kernel_launch(void* const* d_in, const int* in_sizes, int n_in,
                              void* d_out, int out_size, void* d_ws, size_t ws_size,
                              hipStream_t stream) {
  (void)in_sizes; (void)n_in; (void)out_size; (void)ws_size;
  const float* hid = (const float*)d_in[0];
  const float* gw  = (const float*)d_in[1];
  float* out = (float*)d_out;
  char* ws = (char*)d_ws;
  unsigned short* w1 = (unsigned short*)ws;            // dead after k_main
  unsigned short* w2 = (unsigned short*)(ws + WS_W2);  // dead after k_main
  float* part  = (float*)(ws + WS_PART);
  float* bp    = (float*)ws;                           // reuses w1 region

  k_pack  <<<64, 256, 0, stream>>>(gw, w1, w2);
  k_main  <<<256, 512, 0, stream>>>(hid, w1, w2, part);
  k_finish<<<256, 64, 0, stream>>>(part, out, bp);
  k_loss  <<<1, 128, 0, stream>>>(bp, out);
}

// Round 17
// 46.416 us; speedup vs baseline: 3.3301x; 1.2601x over previous
//
#include <hip/hip_runtime.h>
#include <math.h>

#define TOKENS 16384
#define HID    2048
#define NCH    16
#define TPB    128         // tokens per block-group (2 K-split blocks share it)

typedef float f4 __attribute__((ext_vector_type(4)));
typedef short s8v __attribute__((ext_vector_type(8)));

// ws byte layout:
//   w1   [0, 256KB)          bf16 plane1 [64][2048]   (dead after k_main)
//   w2   [256KB, 512KB)      bf16 plane2 [64][2048]   (dead after k_main)
//   part [512KB, 512KB+8MB)  fp32 [2][16384][64] partial logits
//   bp   [0, 128KB)          reuses w1 region (written by k_finish)
//   g2   [131072, +16KB)     stage-1 loss partials [32][128]
#define WS_W2   262144
#define WS_PART 524288
#define WS_G2   131072

__device__ __forceinline__ unsigned short bf16rne(float x) {
  unsigned u = __float_as_uint(x);
  return (unsigned short)((u + 0x7FFFu + ((u >> 16) & 1u)) >> 16);
}

__device__ __forceinline__ void gl16(const void* g, const void* l) {
  __builtin_amdgcn_global_load_lds(
      (const __attribute__((address_space(1))) void*)g,
      (__attribute__((address_space(3))) void*)l, 16, 0, 0);
}

#define BARK(N) { asm volatile("s_waitcnt vmcnt(" #N ") lgkmcnt(0)" ::: "memory"); \
  __builtin_amdgcn_sched_barrier(0); __builtin_amdgcn_s_barrier(); \
  __builtin_amdgcn_sched_barrier(0); }

// fp32 weights -> two bf16 planes (w ~= w1 + w2, residual ~2^-18)
__global__ __launch_bounds__(256) void k_pack(const float* __restrict__ gw,
                                              unsigned short* __restrict__ w1,
                                              unsigned short* __restrict__ w2) {
  int gid = blockIdx.x * 256 + threadIdx.x;   // 16384 threads * 8 els
  int m = gid * 8;
  f4 a = *(const f4*)(gw + m);
  f4 b = *(const f4*)(gw + m + 4);
  float av[8] = {a.x, a.y, a.z, a.w, b.x, b.y, b.z, b.w};
  unsigned short p1[8], p2[8];
  #pragma unroll
  for (int i = 0; i < 8; ++i) {
    unsigned short h = bf16rne(av[i]);
    p1[i] = h;
    float r = av[i] - __uint_as_float((unsigned)h << 16);
    p2[i] = bf16rne(r);
  }
  *(s8v*)(w1 + m) = *(s8v*)p1;
  *(s8v*)(w2 + m) = *(s8v*)p2;
}

__global__ __launch_bounds__(512, 1) void k_main(const float* __restrict__ hid,
                                                 const unsigned short* __restrict__ w1,
                                                 const unsigned short* __restrict__ w2,
                                                 float* __restrict__ part) {
  // 3 buffers * 49152B: A fp32 [128 tok][256B] (32KB) + w1 [64 e][128B] (8KB) + w2 (8KB)
  __shared__ __align__(16) char lds[147456];
  const int tid = threadIdx.x, wave = tid >> 6, lane = tid & 63;
  const int l15 = lane & 15, ks = lane >> 4;
  const int tg = blockIdx.x >> 1, kq = blockIdx.x & 1;   // token-group, K-half
  const int tok0 = tg * TPB;

  // ---- staging sources (64B-line-local granule permutation; LDS dest linear) ----
  const char* hb = (const char*)hid;
  size_t asrc[4]; int adst[4];
  #pragma unroll
  for (int j = 0; j < 4; ++j) {
    int u = j * 512 + tid;
    int row = u >> 4, g = u & 15;
    asrc[j] = (size_t)(tok0 + row) * 8192 + (size_t)kq * 4096
            + (size_t)((g ^ (row & 3)) << 4);
    adst[j] = u * 16;
  }
  // B: waves 0-3 stage w1, waves 4-7 stage w2 (2 granules/thread)
  const char* wpb = (tid < 256) ? (const char*)w1 : (const char*)w2;
  const int bdst0 = (tid < 256) ? 32768 : 40960;
  const int tt = tid & 255;
  size_t bsrc[2]; int bdst[2];
  #pragma unroll
  for (int j = 0; j < 2; ++j) {
    int v = j * 256 + tt;
    int e = v >> 3, g = v & 7;
    bsrc[j] = (size_t)e * 4096 + (size_t)kq * 2048 + (size_t)((g ^ (e & 3)) << 4);
    bdst[j] = bdst0 + v * 16;
  }

  f4 acc[4] = {{0.f,0.f,0.f,0.f},{0.f,0.f,0.f,0.f},{0.f,0.f,0.f,0.f},{0.f,0.f,0.f,0.f}};
  const int arow = wave * 16 + l15, asw = arow & 3;

  auto stage = [&](int c, int bufb) {
    #pragma unroll
    for (int j = 0; j < 4; ++j)
      gl16(hb + asrc[j] + (size_t)c * 256, lds + bufb + adst[j]);
    #pragma unroll
    for (int j = 0; j < 2; ++j)
      gl16(wpb + bsrc[j] + (size_t)c * 128, lds + bufb + bdst[j]);
  };

  auto compute = [&](int bufb) {
    #pragma unroll
    for (int s = 0; s < 2; ++s) {
      int g0 = (s * 8 + ks * 2) ^ asw;
      int g1 = (s * 8 + ks * 2 + 1) ^ asw;
      f4 a0 = *(const f4*)(lds + bufb + arow * 256 + g0 * 16);
      f4 a1 = *(const f4*)(lds + bufb + arow * 256 + g1 * 16);
      float av[8] = {a0.x, a0.y, a0.z, a0.w, a1.x, a1.y, a1.z, a1.w};
      unsigned short p1[8], p2[8];
      #pragma unroll
      for (int i = 0; i < 8; ++i) {
        unsigned short h = bf16rne(av[i]);
        p1[i] = h;
        float r = av[i] - __uint_as_float((unsigned)h << 16);
        p2[i] = bf16rne(r);
      }
      s8v af1 = *(s8v*)p1;
      s8v af2 = *(s8v*)p2;
      #pragma unroll
      for (int nj = 0; nj < 4; ++nj) {
        int e = nj * 16 + l15;
        int g = (s * 4 + ks) ^ (e & 3);
        s8v bw1 = *(const s8v*)(lds + bufb + 32768 + e * 128 + g * 16);
        s8v bw2 = *(const s8v*)(lds + bufb + 40960 + e * 128 + g * 16);
        acc[nj] = __builtin_amdgcn_mfma_f32_16x16x32_bf16(af1, bw1, acc[nj], 0, 0, 0);
        acc[nj] = __builtin_amdgcn_mfma_f32_16x16x32_bf16(af1, bw2, acc[nj], 0, 0, 0);
        acc[nj] = __builtin_amdgcn_mfma_f32_16x16x32_bf16(af2, bw1, acc[nj], 0, 0, 0);
      }
    }
  };

  stage(0, 0);
  stage(1, 49152);
  BARK(6);

  for (int c = 0; c < NCH; ++c) {
    const int bufb = (c % 3) * 49152;
    if (c + 2 < NCH) {
      stage(c + 2, ((c + 2) % 3) * 49152);
      compute(bufb);
      BARK(6);
    } else if (c + 1 < NCH) {
      compute(bufb);
      BARK(0);
    } else {
      compute(bufb);
    }
  }

  // ---- write partial logits: part[kq][token][expert] ----
  #pragma unroll
  for (int nj = 0; nj < 4; ++nj) {
    int e = nj * 16 + l15;
    #pragma unroll
    for (int r = 0; r < 4; ++r) {
      int tl = wave * 16 + ks * 4 + r;
      part[((size_t)kq * TOKENS + (size_t)(tok0 + tl)) * 64 + e] = acc[nj][r];
    }
  }
}

// sum the two K-halves, softmax/top-2; aux partials via LDS transpose
__global__ __launch_bounds__(64) void k_finish(const float* __restrict__ part,
                                               float* __restrict__ out,
                                               float* __restrict__ bp) {
  __shared__ float pr[64][65];   // [token][expert], stride 65 -> conflict-free
  __shared__ float cnt[64];
  const int lane = threadIdx.x;
  const int t = blockIdx.x * 64 + lane;

  cnt[lane] = 0.f;

  float lg[64];
  const float* p0 = part + (size_t)t * 64;
  const float* p1 = part + (size_t)TOKENS * 64 + (size_t)t * 64;
  #pragma unroll
  for (int e = 0; e < 64; e += 4) {
    f4 a = *(const f4*)(p0 + e);
    f4 b = *(const f4*)(p1 + e);
    lg[e]     = a.x + b.x;
    lg[e + 1] = a.y + b.y;
    lg[e + 2] = a.z + b.z;
    lg[e + 3] = a.w + b.w;
  }

  float m = lg[0];
  #pragma unroll
  for (int e = 1; e < 64; ++e) m = fmaxf(m, lg[e]);
  float s = 0.f;
  #pragma unroll
  for (int e = 0; e < 64; ++e) { lg[e] = __expf(lg[e] - m); s += lg[e]; }
  const float inv = 1.f / s;

  // top-2 on exp values (monotone); strict '>' == lax.top_k tie-break
  float b0 = -1.f, b1 = -1.f;
  int i0 = 0, i1 = 0;
  #pragma unroll
  for (int e = 0; e < 64; ++e) {
    float p = lg[e];
    if (p > b0)      { b1 = b0; i1 = i0; b0 = p; i0 = e; }
    else if (p > b1) { b1 = p; i1 = e; }
  }
  const float rs = 1.f / (b0 + b1);
  out[(size_t)t * 2]                  = b0 * rs;
  out[(size_t)t * 2 + 1]              = b1 * rs;
  out[(size_t)TOKENS * 2 + t * 2]     = (float)i0;
  out[(size_t)TOKENS * 2 + t * 2 + 1] = (float)i1;

  // aux partials: write softmax probs row, count top-2 via LDS atomics
  #pragma unroll
  for (int e = 0; e < 64; ++e) pr[lane][e] = lg[e] * inv;
  atomicAdd(&cnt[i0], 1.f);
  atomicAdd(&cnt[i1], 1.f);
  __syncthreads();

  float sp = 0.f;
  #pragma unroll 8
  for (int tt = 0; tt < 64; ++tt) sp += pr[tt][lane];   // expert-column sum
  bp[(size_t)blockIdx.x * 128 + lane]      = sp;
  bp[(size_t)blockIdx.x * 128 + 64 + lane] = cnt[lane];
}

__global__ __launch_bounds__(128) void k_loss1(const float* __restrict__ bp,
                                               float* __restrict__ g2) {
  float s = 0.f;
  #pragma unroll 4
  for (int j = 0; j < 8; ++j)
    s += bp[(size_t)(blockIdx.x * 8 + j) * 128 + threadIdx.x];
  g2[(size_t)blockIdx.x * 128 + threadIdx.x] = s;
}

__global__ __launch_bounds__(128) void k_loss2(const float* __restrict__ g2,
                                               float* __restrict__ out) {
  const int tid = threadIdx.x;
  float s = 0.f;
  #pragma unroll 8
  for (int j = 0; j < 32; ++j) s += g2[(size_t)j * 128 + tid];
  __shared__ float red[128];
  red[tid] = s;
  __syncthreads();
  if (tid < 64) {
    float v = red[tid] * red[64 + tid];   // sumprob_e * count_e
    #pragma unroll
    for (int d = 1; d < 64; d <<= 1) v += __shfl_xor(v, d);
    if (tid == 0)
      out[(size_t)TOKENS * 4] = 0.01f * 64.f * v / (16384.f * 16384.f);
  }
}

extern "C" void kernel_launch(void* const* d_in, const int* in_sizes, int n_in,
                              void* d_out, int out_size, void* d_ws, size_t ws_size,
                              hipStream_t stream) {
  (void)in_sizes; (void)n_in; (void)out_size; (void)ws_size;
  const float* hid = (const float*)d_in[0];
  const float* gw  = (const float*)d_in[1];
  float* out = (float*)d_out;
  char* ws = (char*)d_ws;
  unsigned short* w1 = (unsigned short*)ws;            // dead after k_main
  unsigned short* w2 = (unsigned short*)(ws + WS_W2);  // dead after k_main
  float* part  = (float*)(ws + WS_PART);
  float* bp    = (float*)ws;                           // reuses w1 region
  float* g2    = (float*)(ws + WS_G2);

  k_pack  <<<64, 256, 0, stream>>>(gw, w1, w2);
  k_main  <<<256, 512, 0, stream>>>(hid, w1, w2, part);
  k_finish<<<256, 64, 0, stream>>>(part, out, bp);
  k_loss1 <<<32, 128, 0, stream>>>(bp, g2);
  k_loss2 <<<1, 128, 0, stream>>>(g2, out);
}